// Round 11
// baseline (294.026 us; speedup 1.0000x reference)
//
#include <hip/hip_runtime.h>
#include <hip/hip_bf16.h>
#include <math.h>

#define IN_DIM 256
#define HIDDEN 256
#define HEADS 8
#define FPH 32
#define NCLS 40

typedef __attribute__((ext_vector_type(8))) short bf16x8;
typedef __attribute__((ext_vector_type(4))) float f32x4;

__device__ inline unsigned short f2bf(float f) {
    unsigned int u = __float_as_uint(f);
    unsigned int r = (u + 0x7FFF + ((u >> 16) & 1)) >> 16;
    return (unsigned short)r;
}
__device__ inline float bf2f(unsigned short u) {
    return __uint_as_float(((unsigned int)u) << 16);
}

// ---------------- CSR build ----------------
__global__ void hist_kernel(const int* __restrict__ dst, int* __restrict__ deg, int E) {
    int e = blockIdx.x * blockDim.x + threadIdx.x;
    if (e < E) atomicAdd(&deg[dst[e]], 1);
}

__global__ __launch_bounds__(1024) void scan_blocks_kernel(const int* __restrict__ deg,
                                                           int* __restrict__ excl,
                                                           int* __restrict__ bsum, int N) {
    __shared__ int sm[1024];
    int t = threadIdx.x;
    int g = blockIdx.x * 1024 + t;
    int v = (g < N) ? deg[g] : 0;
    sm[t] = v;
    __syncthreads();
    for (int o = 1; o < 1024; o <<= 1) {
        int add = (t >= o) ? sm[t - o] : 0;
        __syncthreads();
        sm[t] += add;
        __syncthreads();
    }
    if (g < N) excl[g] = sm[t] - v;
    if (t == 1023) bsum[blockIdx.x] = sm[1023];
}

// add_base with inline bsum prefix scan (nb ~ 49, wave-uniform L2-hit loop)
__global__ void add_base_kernel(const int* __restrict__ excl, const int* __restrict__ bsum,
                                int* __restrict__ offs, int* __restrict__ cursor, int N, int nb) {
    int g = blockIdx.x * blockDim.x + threadIdx.x;
    if (g > N) return;
    int nblk = g >> 10;               // uniform within a 256-thread block
    int lim = (g == N) ? nb : nblk;
    int base = 0;
    for (int i = 0; i < lim; i++) base += bsum[i];
    if (g < N) {
        int o = excl[g] + base;
        offs[g] = o;
        cursor[g] = o;
    } else {
        offs[N] = base;               // g == N: base = total
    }
}

__global__ void fill_kernel(const int* __restrict__ src, const int* __restrict__ dst,
                            int* __restrict__ cursor, int* __restrict__ adjsrc, int E) {
    int e = blockIdx.x * blockDim.x + threadIdx.x;
    if (e < E) {
        int d = dst[e];
        int pos = atomicAdd(&cursor[d], 1);
        adjsrc[pos] = src[e];
    }
}

// ---------------- prep: W1^T, W2^T (padded), Aw_eff = W1 @ blockdiag(a) ----------------
// grid = 256 + 48 + 1 blocks x 256 threads
__global__ void prep_kernel(const float* __restrict__ W1, const float* __restrict__ W2,
                            const float* __restrict__ a_src1, const float* __restrict__ a_dst1,
                            unsigned short* __restrict__ W1tb, unsigned short* __restrict__ W2tb,
                            unsigned short* __restrict__ Aw) {
    int bid = blockIdx.x;
    int tid = threadIdx.x;
    if (bid < 256) {
        int t = bid * 256 + tid;
        int c = t & 255, k = t >> 8;
        W1tb[c * 256 + k] = f2bf(W1[k * 256 + c]);
    } else if (bid < 304) {
        int t = (bid - 256) * 256 + tid;
        int c = t >> 8, k = t & 255;
        W2tb[t] = (c < NCLS) ? f2bf(W2[k * NCLS + c]) : (unsigned short)0;
    } else {
        // alpha is linear in h: h.a = x.(W1@a). Aw_eff[c][k] = sum_f W1[k][hd*32+f]*a_sd[hd*32+f],
        // c = 2*hd + sd. Computed f32, rounded to bf16 once.
        int k = tid;
        const float* wrow = &W1[(size_t)k * 256];
#pragma unroll
        for (int c = 0; c < 16; c++) {
            int hd = c >> 1;
            const float* aptr = (c & 1) ? a_dst1 : a_src1;
            float s = 0.f;
#pragma unroll
            for (int f = 0; f < 32; f++) {
                int j = hd * 32 + f;
                s += wrow[j] * aptr[j];
            }
            Aw[c * 256 + k] = f2bf(s);
        }
    }
}

// ---------------- GEMM1 MFMA + fused alpha1 (exact: alpha = x . Aw_eff) ----------------
// One block = 64 rows x all 256 cols + 16 alpha cols. 4 waves, wave w owns rows w*16..+15.
// LDS: K-loop [As 64*40 | Bs 256*40 | Bsa 16*40] = 13440 ush; epilogue Co[64][264] = 16896 ush.
__global__ __launch_bounds__(256) void gemm1_mfma(const float* __restrict__ A,
                                                  const unsigned short* __restrict__ Btb,
                                                  const unsigned short* __restrict__ Aw,
                                                  unsigned short* __restrict__ Cb,
                                                  float* __restrict__ as_o,
                                                  float* __restrict__ ad_o, int M) {
    __shared__ unsigned short smem[64 * 264];  // 16896 >= 13440
    unsigned short* As = smem;
    unsigned short* Bs = smem + 64 * 40;
    unsigned short* Bsa = smem + 64 * 40 + 256 * 40;
    int t = threadIdx.x;
    int wave = t >> 6, lane = t & 63;
    int rowBase = blockIdx.x * 64;
    int lrow = lane & 15, lk = (lane >> 4) * 8;
    f32x4 acc[16] = {};
    f32x4 acca = {};
    int arow = t >> 2, akq = (t & 3) * 8;
    for (int k0 = 0; k0 < 256; k0 += 32) {
        int grow = rowBase + arow;
        float4 a0 = {0.f, 0.f, 0.f, 0.f}, a1 = {0.f, 0.f, 0.f, 0.f};
        if (grow < M) {
            a0 = *reinterpret_cast<const float4*>(&A[(size_t)grow * 256 + k0 + akq]);
            a1 = *reinterpret_cast<const float4*>(&A[(size_t)grow * 256 + k0 + akq + 4]);
        }
        ushort4 p0 = {f2bf(a0.x), f2bf(a0.y), f2bf(a0.z), f2bf(a0.w)};
        ushort4 p1 = {f2bf(a1.x), f2bf(a1.y), f2bf(a1.z), f2bf(a1.w)};
        *reinterpret_cast<ushort4*>(&As[arow * 40 + akq]) = p0;
        *reinterpret_cast<ushort4*>(&As[arow * 40 + akq + 4]) = p1;
#pragma unroll
        for (int q = 0; q < 4; q++) {
            uint4 bv = *reinterpret_cast<const uint4*>(&Btb[(size_t)t * 256 + k0 + q * 8]);
            *reinterpret_cast<uint4*>(&Bs[t * 40 + q * 8]) = bv;
        }
        if (t < 16) {
#pragma unroll
            for (int q = 0; q < 4; q++) {
                uint4 av = *reinterpret_cast<const uint4*>(&Aw[(size_t)t * 256 + k0 + q * 8]);
                *reinterpret_cast<uint4*>(&Bsa[t * 40 + q * 8]) = av;
            }
        }
        __syncthreads();
        bf16x8 a = *reinterpret_cast<const bf16x8*>(&As[(wave * 16 + lrow) * 40 + lk]);
#pragma unroll
        for (int j = 0; j < 16; j++) {
            bf16x8 b = *reinterpret_cast<const bf16x8*>(&Bs[(j * 16 + lrow) * 40 + lk]);
            acc[j] = __builtin_amdgcn_mfma_f32_16x16x32_bf16(a, b, acc[j], 0, 0, 0);
        }
        bf16x8 ba = *reinterpret_cast<const bf16x8*>(&Bsa[lrow * 40 + lk]);
        acca = __builtin_amdgcn_mfma_f32_16x16x32_bf16(a, ba, acca, 0, 0, 0);
        __syncthreads();
    }
    // alpha epilogue: lane holds alpha col c=lrow (head c>>1, src/dst c&1), rows r0..r0+3
    int r0 = (lane >> 4) * 4;
    {
        int c = lrow, hd = c >> 1;
        float* dsts = (c & 1) ? ad_o : as_o;
#pragma unroll
        for (int r = 0; r < 4; r++) {
            int row = rowBase + wave * 16 + r0 + r;
            if (row < M) dsts[row * HEADS + hd] = acca[r];
        }
    }
    // C epilogue: acc -> LDS (bf16) -> coalesced global write
    __syncthreads();
    unsigned short* Co = smem;  // [64][264]
#pragma unroll
    for (int j = 0; j < 16; j++)
#pragma unroll
        for (int r = 0; r < 4; r++)
            Co[(wave * 16 + r0 + r) * 264 + j * 16 + lrow] = f2bf(acc[j][r]);
    __syncthreads();
    int wrow = t >> 2, wchunk = (t & 3) * 64;
    int growW = rowBase + wrow;
    if (growW < M) {
#pragma unroll
        for (int q = 0; q < 8; q++) {
            uint4 v = *reinterpret_cast<const uint4*>(&Co[wrow * 264 + wchunk + q * 8]);
            *reinterpret_cast<uint4*>(&Cb[(size_t)growW * 256 + wchunk + q * 8]) = v;
        }
    }
}

// ---------------- GEMM2 MFMA: out1b [M,256] x W2tb [48,256] -> h2b bf16 [M,48] ----------------
__global__ __launch_bounds__(256) void gemm2_mfma(const unsigned short* __restrict__ Ab,
                                                  const unsigned short* __restrict__ Btb,
                                                  unsigned short* __restrict__ Cb, int M) {
    __shared__ unsigned short As[64 * 40];
    __shared__ unsigned short Bs[48 * 40];
    int t = threadIdx.x;
    int wave = t >> 6, lane = t & 63;
    int rowBase = blockIdx.x * 64;
    int lrow = lane & 15, lk = (lane >> 4) * 8;
    f32x4 acc[3] = {};
    int srow = t >> 2, skq = (t & 3) * 8;
    for (int k0 = 0; k0 < 256; k0 += 32) {
        uint4 av = {0, 0, 0, 0};
        int grow = rowBase + srow;
        if (grow < M) av = *reinterpret_cast<const uint4*>(&Ab[(size_t)grow * 256 + k0 + skq]);
        *reinterpret_cast<uint4*>(&As[srow * 40 + skq]) = av;
        if (t < 192) {
            uint4 bv = *reinterpret_cast<const uint4*>(&Btb[(size_t)srow * 256 + k0 + skq]);
            *reinterpret_cast<uint4*>(&Bs[srow * 40 + skq]) = bv;
        }
        __syncthreads();
        bf16x8 a = *reinterpret_cast<const bf16x8*>(&As[(wave * 16 + lrow) * 40 + lk]);
#pragma unroll
        for (int j = 0; j < 3; j++) {
            bf16x8 b = *reinterpret_cast<const bf16x8*>(&Bs[(j * 16 + lrow) * 40 + lk]);
            acc[j] = __builtin_amdgcn_mfma_f32_16x16x32_bf16(a, b, acc[j], 0, 0, 0);
        }
        __syncthreads();
    }
    int crow0 = rowBase + wave * 16 + (lane >> 4) * 4;
    int ccol = lane & 15;
#pragma unroll
    for (int j = 0; j < 3; j++)
#pragma unroll
        for (int r = 0; r < 4; r++) {
            int row = crow0 + r;
            if (row < M) Cb[(size_t)row * 48 + j * 16 + ccol] = f2bf(acc[j][r]);
        }
}

// ---------------- aggregation layer 1: one wave per node, 8-deep pipelined gather ----------------
__global__ __launch_bounds__(256) void agg1_kernel(const unsigned short* __restrict__ h1b,
                                                   const float* __restrict__ as,
                                                   const float* __restrict__ ad,
                                                   const int* __restrict__ offs,
                                                   const int* __restrict__ adjsrc,
                                                   const float* __restrict__ b,
                                                   unsigned short* __restrict__ outb, int N) {
    int wid = (blockIdx.x * blockDim.x + threadIdx.x) >> 6;
    int lane = threadIdx.x & 63;
    if (wid >= N) return;
    int n = wid;
    int hd = lane >> 3;
    int beg = offs[n], end = offs[n + 1];
    float adh = ad[n * HEADS + hd];
    float ssum = 0.f;
    float4 acc = {0.f, 0.f, 0.f, 0.f};
    int i = beg;
    for (; i + 8 <= end; i += 8) {
        int sidx[8];
        float av[8];
        ushort4 hv[8];
#pragma unroll
        for (int u = 0; u < 8; u++) sidx[u] = adjsrc[i + u];
#pragma unroll
        for (int u = 0; u < 8; u++) av[u] = as[sidx[u] * HEADS + hd];
#pragma unroll
        for (int u = 0; u < 8; u++)
            hv[u] = *reinterpret_cast<const ushort4*>(&h1b[(size_t)sidx[u] * HIDDEN + lane * 4]);
#pragma unroll
        for (int u = 0; u < 8; u++) {
            float e = av[u] + adh;
            e = e > 0.f ? e : 0.2f * e;
            float ex = __expf(e);
            ssum += ex;
            acc.x += ex * bf2f(hv[u].x);
            acc.y += ex * bf2f(hv[u].y);
            acc.z += ex * bf2f(hv[u].z);
            acc.w += ex * bf2f(hv[u].w);
        }
    }
    for (; i + 4 <= end; i += 4) {
        int sidx[4];
        float av[4];
        ushort4 hv[4];
#pragma unroll
        for (int u = 0; u < 4; u++) sidx[u] = adjsrc[i + u];
#pragma unroll
        for (int u = 0; u < 4; u++) av[u] = as[sidx[u] * HEADS + hd];
#pragma unroll
        for (int u = 0; u < 4; u++)
            hv[u] = *reinterpret_cast<const ushort4*>(&h1b[(size_t)sidx[u] * HIDDEN + lane * 4]);
#pragma unroll
        for (int u = 0; u < 4; u++) {
            float e = av[u] + adh;
            e = e > 0.f ? e : 0.2f * e;
            float ex = __expf(e);
            ssum += ex;
            acc.x += ex * bf2f(hv[u].x);
            acc.y += ex * bf2f(hv[u].y);
            acc.z += ex * bf2f(hv[u].z);
            acc.w += ex * bf2f(hv[u].w);
        }
    }
    for (; i < end; i++) {
        int s = adjsrc[i];
        float e = as[s * HEADS + hd] + adh;
        e = e > 0.f ? e : 0.2f * e;
        float ex = __expf(e);
        ssum += ex;
        ushort4 hv = *reinterpret_cast<const ushort4*>(&h1b[(size_t)s * HIDDEN + lane * 4]);
        acc.x += ex * bf2f(hv.x);
        acc.y += ex * bf2f(hv.y);
        acc.z += ex * bf2f(hv.z);
        acc.w += ex * bf2f(hv.w);
    }
    float inv = 1.f / (ssum + 1e-16f);
    int col = lane * 4;
    float4 o;
    o.x = acc.x * inv + b[col + 0];
    o.y = acc.y * inv + b[col + 1];
    o.z = acc.z * inv + b[col + 2];
    o.w = acc.w * inv + b[col + 3];
    o.x = o.x > 0.f ? o.x : expm1f(o.x);
    o.y = o.y > 0.f ? o.y : expm1f(o.y);
    o.z = o.z > 0.f ? o.z : expm1f(o.z);
    o.w = o.w > 0.f ? o.w : expm1f(o.w);
    ushort4 ob;
    ob.x = f2bf(o.x); ob.y = f2bf(o.y); ob.z = f2bf(o.z); ob.w = f2bf(o.w);
    *reinterpret_cast<ushort4*>(&outb[(size_t)n * HIDDEN + col]) = ob;
}

// ---------------- alpha layer 2 (bf16 h2 [M,48]) ----------------
__global__ void alpha2_kernel(const unsigned short* __restrict__ hb, const float* __restrict__ a_src,
                              const float* __restrict__ a_dst, float* __restrict__ as_o,
                              float* __restrict__ ad_o, int N) {
    int n = blockIdx.x * blockDim.x + threadIdx.x;
    if (n >= N) return;
    const unsigned short* hp = &hb[(size_t)n * 48];
    float s = 0.f, d = 0.f;
#pragma unroll
    for (int q = 0; q < 5; q++) {
        uint4 v = *reinterpret_cast<const uint4*>(&hp[q * 8]);
        unsigned int u[4] = {v.x, v.y, v.z, v.w};
#pragma unroll
        for (int e = 0; e < 4; e++) {
            float lo = __uint_as_float(u[e] << 16);
            float hi = __uint_as_float(u[e] & 0xffff0000u);
            int f = q * 8 + e * 2;
            s += lo * a_src[f] + hi * a_src[f + 1];
            d += lo * a_dst[f] + hi * a_dst[f + 1];
        }
    }
    as_o[n] = s;
    ad_o[n] = d;
}

// ---------------- aggregation layer 2: 4-deep pipelined ----------------
__global__ __launch_bounds__(256) void agg2_kernel(const unsigned short* __restrict__ h2b,
                                                   const float* __restrict__ as,
                                                   const float* __restrict__ ad,
                                                   const int* __restrict__ offs,
                                                   const int* __restrict__ adjsrc,
                                                   const float* __restrict__ b,
                                                   float* __restrict__ out, int N) {
    int wid = (blockIdx.x * blockDim.x + threadIdx.x) >> 6;
    int lane = threadIdx.x & 63;
    if (wid >= N) return;
    int n = wid;
    int beg = offs[n], end = offs[n + 1];
    float adh = ad[n];
    float ssum = 0.f;
    float acc = 0.f;
    bool act = lane < NCLS;
    int i = beg;
    for (; i + 4 <= end; i += 4) {
        int s0 = adjsrc[i + 0];
        int s1 = adjsrc[i + 1];
        int s2 = adjsrc[i + 2];
        int s3 = adjsrc[i + 3];
        float a0 = as[s0];
        float a1 = as[s1];
        float a2 = as[s2];
        float a3 = as[s3];
        float h0 = 0.f, h1 = 0.f, h2 = 0.f, h3 = 0.f;
        if (act) {
            h0 = bf2f(h2b[(size_t)s0 * 48 + lane]);
            h1 = bf2f(h2b[(size_t)s1 * 48 + lane]);
            h2 = bf2f(h2b[(size_t)s2 * 48 + lane]);
            h3 = bf2f(h2b[(size_t)s3 * 48 + lane]);
        }
        float e0 = a0 + adh; e0 = e0 > 0.f ? e0 : 0.2f * e0; float x0 = __expf(e0);
        float e1 = a1 + adh; e1 = e1 > 0.f ? e1 : 0.2f * e1; float x1 = __expf(e1);
        float e2 = a2 + adh; e2 = e2 > 0.f ? e2 : 0.2f * e2; float x2 = __expf(e2);
        float e3 = a3 + adh; e3 = e3 > 0.f ? e3 : 0.2f * e3; float x3 = __expf(e3);
        ssum += (x0 + x1) + (x2 + x3);
        acc += x0 * h0 + x1 * h1 + x2 * h2 + x3 * h3;
    }
    for (; i < end; i++) {
        int s = adjsrc[i];
        float e = as[s] + adh;
        e = e > 0.f ? e : 0.2f * e;
        float ex = __expf(e);
        ssum += ex;
        if (act) acc += ex * bf2f(h2b[(size_t)s * 48 + lane]);
    }
    if (act) {
        float inv = 1.f / (ssum + 1e-16f);
        out[(size_t)n * NCLS + lane] = acc * inv + b[lane];
    }
}

extern "C" void kernel_launch(void* const* d_in, const int* in_sizes, int n_in,
                              void* d_out, int out_size, void* d_ws, size_t ws_size,
                              hipStream_t stream) {
    const float* x      = (const float*)d_in[0];
    const int*   ei     = (const int*)d_in[1];
    const float* W1     = (const float*)d_in[2];
    const float* a_src1 = (const float*)d_in[3];
    const float* a_dst1 = (const float*)d_in[4];
    const float* b1     = (const float*)d_in[5];
    const float* W2     = (const float*)d_in[6];
    const float* a_src2 = (const float*)d_in[7];
    const float* a_dst2 = (const float*)d_in[8];
    const float* b2     = (const float*)d_in[9];
    float* out = (float*)d_out;

    const int N = in_sizes[0] / IN_DIM;
    const int E = in_sizes[1] / 2;
    const int* src = ei;
    const int* dst = ei + E;

    char* ws = (char*)d_ws;
    size_t off = 0;
    auto alloc = [&](size_t bytes) {
        void* p = ws + off;
        off = (off + bytes + 255) & ~(size_t)255;
        return p;
    };
    int*   deg    = (int*)alloc((size_t)N * 4);
    int*   excl   = (int*)alloc((size_t)N * 4);
    int*   bsum   = (int*)alloc((size_t)256 * 4);
    int*   cursor = (int*)alloc((size_t)N * 4);
    int*   offs   = (int*)alloc((size_t)(N + 1) * 4);
    int*   adjsrc = (int*)alloc((size_t)E * 4);
    unsigned short* W1tb  = (unsigned short*)alloc((size_t)256 * 256 * 2);
    unsigned short* W2tb  = (unsigned short*)alloc((size_t)48 * 256 * 2);
    unsigned short* Aw    = (unsigned short*)alloc((size_t)16 * 256 * 2);
    unsigned short* h1b   = (unsigned short*)alloc((size_t)N * HIDDEN * 2);
    unsigned short* out1b = (unsigned short*)alloc((size_t)N * HIDDEN * 2);
    unsigned short* h2b   = (unsigned short*)alloc((size_t)N * 48 * 2);
    float* as1    = (float*)alloc((size_t)N * HEADS * 4);
    float* ad1    = (float*)alloc((size_t)N * HEADS * 4);
    float* as2    = (float*)alloc((size_t)N * 4);
    float* ad2    = (float*)alloc((size_t)N * 4);

    const int nb = (N + 1023) / 1024;

    hipMemsetAsync(deg, 0, (size_t)N * 4, stream);
    hist_kernel<<<dim3((E + 255) / 256), dim3(256), 0, stream>>>(dst, deg, E);
    scan_blocks_kernel<<<dim3(nb), dim3(1024), 0, stream>>>(deg, excl, bsum, N);
    add_base_kernel<<<dim3((N + 256) / 256), dim3(256), 0, stream>>>(excl, bsum, offs, cursor, N, nb);
    fill_kernel<<<dim3((E + 255) / 256), dim3(256), 0, stream>>>(src, dst, cursor, adjsrc, E);

    prep_kernel<<<dim3(305), dim3(256), 0, stream>>>(W1, W2, a_src1, a_dst1, W1tb, W2tb, Aw);

    gemm1_mfma<<<dim3((N + 63) / 64), dim3(256), 0, stream>>>(x, W1tb, Aw, h1b, as1, ad1, N);
    agg1_kernel<<<dim3((N + 3) / 4), dim3(256), 0, stream>>>(h1b, as1, ad1, offs, adjsrc, b1, out1b, N);

    gemm2_mfma<<<dim3((N + 63) / 64), dim3(256), 0, stream>>>(out1b, W2tb, h2b, N);
    alpha2_kernel<<<dim3((N + 255) / 256), dim3(256), 0, stream>>>(h2b, a_src2, a_dst2, as2, ad2, N);
    agg2_kernel<<<dim3((N + 3) / 4), dim3(256), 0, stream>>>(h2b, as2, ad2, offs, adjsrc, b2, out, N);
}

// Round 12
// 264.074 us; speedup vs baseline: 1.1134x; 1.1134x over previous
//
#include <hip/hip_runtime.h>
#include <hip/hip_bf16.h>
#include <math.h>

#define IN_DIM 256
#define HIDDEN 256
#define HEADS 8
#define FPH 32
#define NCLS 40

typedef __attribute__((ext_vector_type(8))) short bf16x8;
typedef __attribute__((ext_vector_type(4))) float f32x4;

__device__ inline unsigned short f2bf(float f) {
    unsigned int u = __float_as_uint(f);
    unsigned int r = (u + 0x7FFF + ((u >> 16) & 1)) >> 16;
    return (unsigned short)r;
}
__device__ inline float bf2f(unsigned short u) {
    return __uint_as_float(((unsigned int)u) << 16);
}

// ---------------- CSR build ----------------
__global__ void hist_kernel(const int* __restrict__ dst, int* __restrict__ deg, int E) {
    int e = blockIdx.x * blockDim.x + threadIdx.x;
    if (e < E) atomicAdd(&deg[dst[e]], 1);
}

__global__ __launch_bounds__(1024) void scan_blocks_kernel(const int* __restrict__ deg,
                                                           int* __restrict__ excl,
                                                           int* __restrict__ bsum, int N) {
    __shared__ int sm[1024];
    int t = threadIdx.x;
    int g = blockIdx.x * 1024 + t;
    int v = (g < N) ? deg[g] : 0;
    sm[t] = v;
    __syncthreads();
    for (int o = 1; o < 1024; o <<= 1) {
        int add = (t >= o) ? sm[t - o] : 0;
        __syncthreads();
        sm[t] += add;
        __syncthreads();
    }
    if (g < N) excl[g] = sm[t] - v;
    if (t == 1023) bsum[blockIdx.x] = sm[1023];
}

// add_base with inline bsum prefix scan (nb ~ 49, wave-uniform L2-hit loop)
__global__ void add_base_kernel(const int* __restrict__ excl, const int* __restrict__ bsum,
                                int* __restrict__ offs, int* __restrict__ cursor, int N, int nb) {
    int g = blockIdx.x * blockDim.x + threadIdx.x;
    if (g > N) return;
    int nblk = g >> 10;               // uniform within a 256-thread block
    int lim = (g == N) ? nb : nblk;
    int base = 0;
    for (int i = 0; i < lim; i++) base += bsum[i];
    if (g < N) {
        int o = excl[g] + base;
        offs[g] = o;
        cursor[g] = o;
    } else {
        offs[N] = base;               // g == N: base = total
    }
}

__global__ void fill_kernel(const int* __restrict__ src, const int* __restrict__ dst,
                            int* __restrict__ cursor, int* __restrict__ adjsrc, int E) {
    int e = blockIdx.x * blockDim.x + threadIdx.x;
    if (e < E) {
        int d = dst[e];
        int pos = atomicAdd(&cursor[d], 1);
        adjsrc[pos] = src[e];
    }
}

// ---------------- prep: W1^T + Aw_eff (fused, coalesced), W2^T (padded) ----------------
// grid = 256 + 48 blocks x 256 threads.
// Block k<256: reads W1 row k coalesced; writes W1tb[:,k]; computes Aw_eff[c][k] via
// 32-lane segmented shfl reduction of w*a_src/dst (alpha is linear: h.a = x.(W1@a)).
__global__ void prep_kernel(const float* __restrict__ W1, const float* __restrict__ W2,
                            const float* __restrict__ a_src1, const float* __restrict__ a_dst1,
                            unsigned short* __restrict__ W1tb, unsigned short* __restrict__ W2tb,
                            unsigned short* __restrict__ Aw) {
    int bid = blockIdx.x;
    int tid = threadIdx.x;
    if (bid < 256) {
        int k = bid, j = tid;
        float w = W1[(size_t)k * 256 + j];
        W1tb[(size_t)j * 256 + k] = f2bf(w);
        float s = w * a_src1[j];
        float d = w * a_dst1[j];
#pragma unroll
        for (int m = 1; m < 32; m <<= 1) {
            s += __shfl_xor(s, m, 64);
            d += __shfl_xor(d, m, 64);
        }
        if ((j & 31) == 0) {
            int hd = j >> 5;
            Aw[(size_t)(2 * hd) * 256 + k]     = f2bf(s);
            Aw[(size_t)(2 * hd + 1) * 256 + k] = f2bf(d);
        }
    } else {
        int t = (bid - 256) * 256 + tid;
        int c = t >> 8, k = t & 255;
        W2tb[t] = (c < NCLS) ? f2bf(W2[k * NCLS + c]) : (unsigned short)0;
    }
}

// ---------------- GEMM1 MFMA + fused alpha1 (exact: alpha = x . Aw_eff) ----------------
// One block = 64 rows x all 256 cols + 16 alpha cols. 4 waves, wave w owns rows w*16..+15.
// LDS: K-loop [As 64*40 | Bs 256*40 | Bsa 16*40] = 13440 ush; epilogue Co[64][264] = 16896 ush.
__global__ __launch_bounds__(256) void gemm1_mfma(const float* __restrict__ A,
                                                  const unsigned short* __restrict__ Btb,
                                                  const unsigned short* __restrict__ Aw,
                                                  unsigned short* __restrict__ Cb,
                                                  float* __restrict__ as_o,
                                                  float* __restrict__ ad_o, int M) {
    __shared__ unsigned short smem[64 * 264];  // 16896 >= 13440
    unsigned short* As = smem;
    unsigned short* Bs = smem + 64 * 40;
    unsigned short* Bsa = smem + 64 * 40 + 256 * 40;
    int t = threadIdx.x;
    int wave = t >> 6, lane = t & 63;
    int rowBase = blockIdx.x * 64;
    int lrow = lane & 15, lk = (lane >> 4) * 8;
    f32x4 acc[16] = {};
    f32x4 acca = {};
    int arow = t >> 2, akq = (t & 3) * 8;
    for (int k0 = 0; k0 < 256; k0 += 32) {
        int grow = rowBase + arow;
        float4 a0 = {0.f, 0.f, 0.f, 0.f}, a1 = {0.f, 0.f, 0.f, 0.f};
        if (grow < M) {
            a0 = *reinterpret_cast<const float4*>(&A[(size_t)grow * 256 + k0 + akq]);
            a1 = *reinterpret_cast<const float4*>(&A[(size_t)grow * 256 + k0 + akq + 4]);
        }
        ushort4 p0 = {f2bf(a0.x), f2bf(a0.y), f2bf(a0.z), f2bf(a0.w)};
        ushort4 p1 = {f2bf(a1.x), f2bf(a1.y), f2bf(a1.z), f2bf(a1.w)};
        *reinterpret_cast<ushort4*>(&As[arow * 40 + akq]) = p0;
        *reinterpret_cast<ushort4*>(&As[arow * 40 + akq + 4]) = p1;
#pragma unroll
        for (int q = 0; q < 4; q++) {
            uint4 bv = *reinterpret_cast<const uint4*>(&Btb[(size_t)t * 256 + k0 + q * 8]);
            *reinterpret_cast<uint4*>(&Bs[t * 40 + q * 8]) = bv;
        }
        if (t < 16) {
#pragma unroll
            for (int q = 0; q < 4; q++) {
                uint4 av = *reinterpret_cast<const uint4*>(&Aw[(size_t)t * 256 + k0 + q * 8]);
                *reinterpret_cast<uint4*>(&Bsa[t * 40 + q * 8]) = av;
            }
        }
        __syncthreads();
        bf16x8 a = *reinterpret_cast<const bf16x8*>(&As[(wave * 16 + lrow) * 40 + lk]);
#pragma unroll
        for (int j = 0; j < 16; j++) {
            bf16x8 b = *reinterpret_cast<const bf16x8*>(&Bs[(j * 16 + lrow) * 40 + lk]);
            acc[j] = __builtin_amdgcn_mfma_f32_16x16x32_bf16(a, b, acc[j], 0, 0, 0);
        }
        bf16x8 ba = *reinterpret_cast<const bf16x8*>(&Bsa[lrow * 40 + lk]);
        acca = __builtin_amdgcn_mfma_f32_16x16x32_bf16(a, ba, acca, 0, 0, 0);
        __syncthreads();
    }
    // alpha epilogue: lane holds alpha col c=lrow (head c>>1, src/dst c&1), rows r0..r0+3
    int r0 = (lane >> 4) * 4;
    {
        int c = lrow, hd = c >> 1;
        float* dsts = (c & 1) ? ad_o : as_o;
#pragma unroll
        for (int r = 0; r < 4; r++) {
            int row = rowBase + wave * 16 + r0 + r;
            if (row < M) dsts[row * HEADS + hd] = acca[r];
        }
    }
    // C epilogue: acc -> LDS (bf16) -> coalesced global write
    __syncthreads();
    unsigned short* Co = smem;  // [64][264]
#pragma unroll
    for (int j = 0; j < 16; j++)
#pragma unroll
        for (int r = 0; r < 4; r++)
            Co[(wave * 16 + r0 + r) * 264 + j * 16 + lrow] = f2bf(acc[j][r]);
    __syncthreads();
    int wrow = t >> 2, wchunk = (t & 3) * 64;
    int growW = rowBase + wrow;
    if (growW < M) {
#pragma unroll
        for (int q = 0; q < 8; q++) {
            uint4 v = *reinterpret_cast<const uint4*>(&Co[wrow * 264 + wchunk + q * 8]);
            *reinterpret_cast<uint4*>(&Cb[(size_t)growW * 256 + wchunk + q * 8]) = v;
        }
    }
}

// ---------------- GEMM2 MFMA: out1b [M,256] x W2tb [48,256] -> h2b bf16 [M,48] ----------------
__global__ __launch_bounds__(256) void gemm2_mfma(const unsigned short* __restrict__ Ab,
                                                  const unsigned short* __restrict__ Btb,
                                                  unsigned short* __restrict__ Cb, int M) {
    __shared__ unsigned short As[64 * 40];
    __shared__ unsigned short Bs[48 * 40];
    int t = threadIdx.x;
    int wave = t >> 6, lane = t & 63;
    int rowBase = blockIdx.x * 64;
    int lrow = lane & 15, lk = (lane >> 4) * 8;
    f32x4 acc[3] = {};
    int srow = t >> 2, skq = (t & 3) * 8;
    for (int k0 = 0; k0 < 256; k0 += 32) {
        uint4 av = {0, 0, 0, 0};
        int grow = rowBase + srow;
        if (grow < M) av = *reinterpret_cast<const uint4*>(&Ab[(size_t)grow * 256 + k0 + skq]);
        *reinterpret_cast<uint4*>(&As[srow * 40 + skq]) = av;
        if (t < 192) {
            uint4 bv = *reinterpret_cast<const uint4*>(&Btb[(size_t)srow * 256 + k0 + skq]);
            *reinterpret_cast<uint4*>(&Bs[srow * 40 + skq]) = bv;
        }
        __syncthreads();
        bf16x8 a = *reinterpret_cast<const bf16x8*>(&As[(wave * 16 + lrow) * 40 + lk]);
#pragma unroll
        for (int j = 0; j < 3; j++) {
            bf16x8 b = *reinterpret_cast<const bf16x8*>(&Bs[(j * 16 + lrow) * 40 + lk]);
            acc[j] = __builtin_amdgcn_mfma_f32_16x16x32_bf16(a, b, acc[j], 0, 0, 0);
        }
        __syncthreads();
    }
    int crow0 = rowBase + wave * 16 + (lane >> 4) * 4;
    int ccol = lane & 15;
#pragma unroll
    for (int j = 0; j < 3; j++)
#pragma unroll
        for (int r = 0; r < 4; r++) {
            int row = crow0 + r;
            if (row < M) Cb[(size_t)row * 48 + j * 16 + ccol] = f2bf(acc[j][r]);
        }
}

// ---------------- aggregation layer 1: one wave per node, 8-deep pipelined gather ----------------
__global__ __launch_bounds__(256) void agg1_kernel(const unsigned short* __restrict__ h1b,
                                                   const float* __restrict__ as,
                                                   const float* __restrict__ ad,
                                                   const int* __restrict__ offs,
                                                   const int* __restrict__ adjsrc,
                                                   const float* __restrict__ b,
                                                   unsigned short* __restrict__ outb, int N) {
    int wid = (blockIdx.x * blockDim.x + threadIdx.x) >> 6;
    int lane = threadIdx.x & 63;
    if (wid >= N) return;
    int n = wid;
    int hd = lane >> 3;
    int beg = offs[n], end = offs[n + 1];
    float adh = ad[n * HEADS + hd];
    float ssum = 0.f;
    float4 acc = {0.f, 0.f, 0.f, 0.f};
    int i = beg;
    for (; i + 8 <= end; i += 8) {
        int sidx[8];
        float av[8];
        ushort4 hv[8];
#pragma unroll
        for (int u = 0; u < 8; u++) sidx[u] = adjsrc[i + u];
#pragma unroll
        for (int u = 0; u < 8; u++) av[u] = as[sidx[u] * HEADS + hd];
#pragma unroll
        for (int u = 0; u < 8; u++)
            hv[u] = *reinterpret_cast<const ushort4*>(&h1b[(size_t)sidx[u] * HIDDEN + lane * 4]);
#pragma unroll
        for (int u = 0; u < 8; u++) {
            float e = av[u] + adh;
            e = e > 0.f ? e : 0.2f * e;
            float ex = __expf(e);
            ssum += ex;
            acc.x += ex * bf2f(hv[u].x);
            acc.y += ex * bf2f(hv[u].y);
            acc.z += ex * bf2f(hv[u].z);
            acc.w += ex * bf2f(hv[u].w);
        }
    }
    for (; i + 4 <= end; i += 4) {
        int sidx[4];
        float av[4];
        ushort4 hv[4];
#pragma unroll
        for (int u = 0; u < 4; u++) sidx[u] = adjsrc[i + u];
#pragma unroll
        for (int u = 0; u < 4; u++) av[u] = as[sidx[u] * HEADS + hd];
#pragma unroll
        for (int u = 0; u < 4; u++)
            hv[u] = *reinterpret_cast<const ushort4*>(&h1b[(size_t)sidx[u] * HIDDEN + lane * 4]);
#pragma unroll
        for (int u = 0; u < 4; u++) {
            float e = av[u] + adh;
            e = e > 0.f ? e : 0.2f * e;
            float ex = __expf(e);
            ssum += ex;
            acc.x += ex * bf2f(hv[u].x);
            acc.y += ex * bf2f(hv[u].y);
            acc.z += ex * bf2f(hv[u].z);
            acc.w += ex * bf2f(hv[u].w);
        }
    }
    for (; i < end; i++) {
        int s = adjsrc[i];
        float e = as[s * HEADS + hd] + adh;
        e = e > 0.f ? e : 0.2f * e;
        float ex = __expf(e);
        ssum += ex;
        ushort4 hv = *reinterpret_cast<const ushort4*>(&h1b[(size_t)s * HIDDEN + lane * 4]);
        acc.x += ex * bf2f(hv.x);
        acc.y += ex * bf2f(hv.y);
        acc.z += ex * bf2f(hv.z);
        acc.w += ex * bf2f(hv.w);
    }
    float inv = 1.f / (ssum + 1e-16f);
    int col = lane * 4;
    float4 o;
    o.x = acc.x * inv + b[col + 0];
    o.y = acc.y * inv + b[col + 1];
    o.z = acc.z * inv + b[col + 2];
    o.w = acc.w * inv + b[col + 3];
    o.x = o.x > 0.f ? o.x : expm1f(o.x);
    o.y = o.y > 0.f ? o.y : expm1f(o.y);
    o.z = o.z > 0.f ? o.z : expm1f(o.z);
    o.w = o.w > 0.f ? o.w : expm1f(o.w);
    ushort4 ob;
    ob.x = f2bf(o.x); ob.y = f2bf(o.y); ob.z = f2bf(o.z); ob.w = f2bf(o.w);
    *reinterpret_cast<ushort4*>(&outb[(size_t)n * HIDDEN + col]) = ob;
}

// ---------------- alpha layer 2 (bf16 h2 [M,48]) ----------------
__global__ void alpha2_kernel(const unsigned short* __restrict__ hb, const float* __restrict__ a_src,
                              const float* __restrict__ a_dst, float* __restrict__ as_o,
                              float* __restrict__ ad_o, int N) {
    int n = blockIdx.x * blockDim.x + threadIdx.x;
    if (n >= N) return;
    const unsigned short* hp = &hb[(size_t)n * 48];
    float s = 0.f, d = 0.f;
#pragma unroll
    for (int q = 0; q < 5; q++) {
        uint4 v = *reinterpret_cast<const uint4*>(&hp[q * 8]);
        unsigned int u[4] = {v.x, v.y, v.z, v.w};
#pragma unroll
        for (int e = 0; e < 4; e++) {
            float lo = __uint_as_float(u[e] << 16);
            float hi = __uint_as_float(u[e] & 0xffff0000u);
            int f = q * 8 + e * 2;
            s += lo * a_src[f] + hi * a_src[f + 1];
            d += lo * a_dst[f] + hi * a_dst[f + 1];
        }
    }
    as_o[n] = s;
    ad_o[n] = d;
}

// ---------------- aggregation layer 2: 4-deep pipelined ----------------
__global__ __launch_bounds__(256) void agg2_kernel(const unsigned short* __restrict__ h2b,
                                                   const float* __restrict__ as,
                                                   const float* __restrict__ ad,
                                                   const int* __restrict__ offs,
                                                   const int* __restrict__ adjsrc,
                                                   const float* __restrict__ b,
                                                   float* __restrict__ out, int N) {
    int wid = (blockIdx.x * blockDim.x + threadIdx.x) >> 6;
    int lane = threadIdx.x & 63;
    if (wid >= N) return;
    int n = wid;
    int beg = offs[n], end = offs[n + 1];
    float adh = ad[n];
    float ssum = 0.f;
    float acc = 0.f;
    bool act = lane < NCLS;
    int i = beg;
    for (; i + 4 <= end; i += 4) {
        int s0 = adjsrc[i + 0];
        int s1 = adjsrc[i + 1];
        int s2 = adjsrc[i + 2];
        int s3 = adjsrc[i + 3];
        float a0 = as[s0];
        float a1 = as[s1];
        float a2 = as[s2];
        float a3 = as[s3];
        float h0 = 0.f, h1 = 0.f, h2 = 0.f, h3 = 0.f;
        if (act) {
            h0 = bf2f(h2b[(size_t)s0 * 48 + lane]);
            h1 = bf2f(h2b[(size_t)s1 * 48 + lane]);
            h2 = bf2f(h2b[(size_t)s2 * 48 + lane]);
            h3 = bf2f(h2b[(size_t)s3 * 48 + lane]);
        }
        float e0 = a0 + adh; e0 = e0 > 0.f ? e0 : 0.2f * e0; float x0 = __expf(e0);
        float e1 = a1 + adh; e1 = e1 > 0.f ? e1 : 0.2f * e1; float x1 = __expf(e1);
        float e2 = a2 + adh; e2 = e2 > 0.f ? e2 : 0.2f * e2; float x2 = __expf(e2);
        float e3 = a3 + adh; e3 = e3 > 0.f ? e3 : 0.2f * e3; float x3 = __expf(e3);
        ssum += (x0 + x1) + (x2 + x3);
        acc += x0 * h0 + x1 * h1 + x2 * h2 + x3 * h3;
    }
    for (; i < end; i++) {
        int s = adjsrc[i];
        float e = as[s] + adh;
        e = e > 0.f ? e : 0.2f * e;
        float ex = __expf(e);
        ssum += ex;
        if (act) acc += ex * bf2f(h2b[(size_t)s * 48 + lane]);
    }
    if (act) {
        float inv = 1.f / (ssum + 1e-16f);
        out[(size_t)n * NCLS + lane] = acc * inv + b[lane];
    }
}

extern "C" void kernel_launch(void* const* d_in, const int* in_sizes, int n_in,
                              void* d_out, int out_size, void* d_ws, size_t ws_size,
                              hipStream_t stream) {
    const float* x      = (const float*)d_in[0];
    const int*   ei     = (const int*)d_in[1];
    const float* W1     = (const float*)d_in[2];
    const float* a_src1 = (const float*)d_in[3];
    const float* a_dst1 = (const float*)d_in[4];
    const float* b1     = (const float*)d_in[5];
    const float* W2     = (const float*)d_in[6];
    const float* a_src2 = (const float*)d_in[7];
    const float* a_dst2 = (const float*)d_in[8];
    const float* b2     = (const float*)d_in[9];
    float* out = (float*)d_out;

    const int N = in_sizes[0] / IN_DIM;
    const int E = in_sizes[1] / 2;
    const int* src = ei;
    const int* dst = ei + E;

    char* ws = (char*)d_ws;
    size_t off = 0;
    auto alloc = [&](size_t bytes) {
        void* p = ws + off;
        off = (off + bytes + 255) & ~(size_t)255;
        return p;
    };
    int*   deg    = (int*)alloc((size_t)N * 4);
    int*   excl   = (int*)alloc((size_t)N * 4);
    int*   bsum   = (int*)alloc((size_t)256 * 4);
    int*   cursor = (int*)alloc((size_t)N * 4);
    int*   offs   = (int*)alloc((size_t)(N + 1) * 4);
    int*   adjsrc = (int*)alloc((size_t)E * 4);
    unsigned short* W1tb  = (unsigned short*)alloc((size_t)256 * 256 * 2);
    unsigned short* W2tb  = (unsigned short*)alloc((size_t)48 * 256 * 2);
    unsigned short* Aw    = (unsigned short*)alloc((size_t)16 * 256 * 2);
    unsigned short* h1b   = (unsigned short*)alloc((size_t)N * HIDDEN * 2);
    unsigned short* out1b = (unsigned short*)alloc((size_t)N * HIDDEN * 2);
    unsigned short* h2b   = (unsigned short*)alloc((size_t)N * 48 * 2);
    float* as1    = (float*)alloc((size_t)N * HEADS * 4);
    float* ad1    = (float*)alloc((size_t)N * HEADS * 4);
    float* as2    = (float*)alloc((size_t)N * 4);
    float* ad2    = (float*)alloc((size_t)N * 4);

    const int nb = (N + 1023) / 1024;

    hipMemsetAsync(deg, 0, (size_t)N * 4, stream);
    hist_kernel<<<dim3((E + 255) / 256), dim3(256), 0, stream>>>(dst, deg, E);
    scan_blocks_kernel<<<dim3(nb), dim3(1024), 0, stream>>>(deg, excl, bsum, N);
    add_base_kernel<<<dim3((N + 256) / 256), dim3(256), 0, stream>>>(excl, bsum, offs, cursor, N, nb);
    fill_kernel<<<dim3((E + 255) / 256), dim3(256), 0, stream>>>(src, dst, cursor, adjsrc, E);

    prep_kernel<<<dim3(304), dim3(256), 0, stream>>>(W1, W2, a_src1, a_dst1, W1tb, W2tb, Aw);

    gemm1_mfma<<<dim3((N + 63) / 64), dim3(256), 0, stream>>>(x, W1tb, Aw, h1b, as1, ad1, N);
    agg1_kernel<<<dim3((N + 3) / 4), dim3(256), 0, stream>>>(h1b, as1, ad1, offs, adjsrc, b1, out1b, N);

    gemm2_mfma<<<dim3((N + 63) / 64), dim3(256), 0, stream>>>(out1b, W2tb, h2b, N);
    alpha2_kernel<<<dim3((N + 255) / 256), dim3(256), 0, stream>>>(h2b, a_src2, a_dst2, as2, ad2, N);
    agg2_kernel<<<dim3((N + 3) / 4), dim3(256), 0, stream>>>(h2b, as2, ad2, offs, adjsrc, b2, out, N);
}